// Round 11
// baseline (442.450 us; speedup 1.0000x reference)
//
#include <hip/hip_runtime.h>
#include <stdint.h>

// SOM BMU search: B=8192 inputs [B,256], codebook [16384,256].
// argmin_n ||x-w_n|| == argmin_n (w2[n] - 2 x.w_n)  (x2 per-row constant).
// Engine: bf16 hi/lo split GEMM on MFMA (xh.wh + xh.wl + xl.wh).
// R11: W-RESIDENT blocks. Each block owns a 128-col W strip: B_hi in 128
// VGPRs + B_lo in 64KB LDS, loaded ONCE; streams 1024 X rows reading only
// A fragments (halves per-K-tile traffic vs R10, which was vector-memory
// bound at ~27 B/cyc/CU). Zero barriers in main loop; LDS read-only.

#define B_DIM 8192
#define V_DIM 256
#define N_DIM 16384

#define WS_W2_OFF     0
#define WS_PACKED_OFF 65536
#define WS_PLANES_OFF 131072
#define XPLANE_BYTES  (B_DIM * V_DIM * 2)   // 4MB
#define WPLANE_BYTES  (N_DIM * V_DIM * 2)   // 8MB
#define WS_FAST_NEED  (WS_PLANES_OFF + 2 * XPLANE_BYTES + 2 * WPLANE_BYTES)

typedef __attribute__((ext_vector_type(8))) short short8;
typedef __attribute__((ext_vector_type(4))) float f32x4;

__device__ __forceinline__ unsigned long long packKey(float s, unsigned idx) {
    unsigned u = __float_as_uint(s);
    u = (u & 0x80000000u) ? ~u : (u | 0x80000000u);
    return ((unsigned long long)u << 32) | (unsigned long long)idx;
}

__global__ __launch_bounds__(256) void w2_kernel(const float* __restrict__ W,
                                                 float* __restrict__ w2) {
    int lane = threadIdx.x & 63;
    int wv   = threadIdx.x >> 6;
    int n    = blockIdx.x * 4 + wv;
    float4 v = ((const float4*)(W + (size_t)n * V_DIM))[lane];
    float s = v.x * v.x + v.y * v.y + v.z * v.z + v.w * v.w;
    #pragma unroll
    for (int m = 32; m >= 1; m >>= 1) s += __shfl_xor(s, m);
    if (lane == 0) w2[n] = s;
}

// ---------------- fast path ----------------

__device__ __forceinline__ unsigned bfrn(float x) { // RNE f32->bf16
    unsigned u = __float_as_uint(x);
    return (u + 0x7FFFu + ((u >> 16) & 1u)) >> 16;
}
__device__ __forceinline__ float bf2f(unsigned h) { return __uint_as_float(h << 16); }

__device__ __forceinline__ void hilo8(const float4& a, const float4& b,
                                      uint4& hp, uint4& lp) {
    float v[8] = {a.x, a.y, a.z, a.w, b.x, b.y, b.z, b.w};
    unsigned hi[8], lo[8];
    #pragma unroll
    for (int i = 0; i < 8; ++i) {
        hi[i] = bfrn(v[i]);
        lo[i] = bfrn(v[i] - bf2f(hi[i]));
    }
    hp.x = hi[0] | (hi[1] << 16); hp.y = hi[2] | (hi[3] << 16);
    hp.z = hi[4] | (hi[5] << 16); hp.w = hi[6] | (hi[7] << 16);
    lp.x = lo[0] | (lo[1] << 16); lp.y = lo[2] | (lo[3] << 16);
    lp.z = lo[4] | (lo[5] << 16); lp.w = lo[6] | (lo[7] << 16);
}

// Fragment-major planes for BOTH X and W (R8/R10 layout, proven):
//   F[chunk16][ks][lane][8bf16], addr = ((chunk*8 + ks)*64 + lane)*16B
//   chunk = row/16; lane l covers row chunk*16+(l&15), k = ks*32+(l>>4)*8..+8
// == exact mfma_16x16x32_bf16 operand fragment; a wave reads 1KB contiguous.
__global__ __launch_bounds__(256) void convert_planes(const float* __restrict__ X,
                                                      const float* __restrict__ W,
                                                      unsigned short* __restrict__ Xfh,
                                                      unsigned short* __restrict__ Xfl,
                                                      unsigned short* __restrict__ Wfh,
                                                      unsigned short* __restrict__ Wfl) {
    const int gid = blockIdx.x * 256 + threadIdx.x;
    const float* src;
    unsigned short *dh, *dl;
    int tid;
    if (blockIdx.x < 1024) { // X: 512 chunks * 8 ks * 64 lanes = 262144
        tid = gid;
        const int lane = tid & 63, ck = tid >> 6;
        const int ks = ck & 7, chunk = ck >> 3;
        const int row = chunk * 16 + (lane & 15);
        const int k0  = ks * 32 + (lane >> 4) * 8;
        src = X + (size_t)row * V_DIM + k0;
        dh = Xfh; dl = Xfl;
    } else {                 // W: 1024 chunks -> 524288
        tid = gid - 262144;
        const int lane = tid & 63, ck = tid >> 6;
        const int ks = ck & 7, chunk = ck >> 3;
        const int row = chunk * 16 + (lane & 15);
        const int k0  = ks * 32 + (lane >> 4) * 8;
        src = W + (size_t)row * V_DIM + k0;
        dh = Wfh; dl = Wfl;
    }
    float4 a = ((const float4*)src)[0];
    float4 b = ((const float4*)src)[1];
    uint4 hp, lp; hilo8(a, b, hp, lp);
    *(uint4*)(dh + (size_t)tid * 8) = hp;
    *(uint4*)(dl + (size_t)tid * 8) = lp;
}

__device__ __forceinline__ void gl16(const void* g, void* l) {
    __builtin_amdgcn_global_load_lds((const __attribute__((address_space(1))) unsigned int*)g,
                                     (__attribute__((address_space(3))) unsigned int*)l,
                                     16, 0, 0);
}

// 256 threads (4 waves 2x2): block tile = 128 X-rows/pass x 128 W-cols.
// Wave tile 64x64. W strip resident: B_hi bh[4][8] in regs (128 VGPR),
// B_lo in 64KB LDS. 8 passes x 8 K-tiles over the block's 1024 X rows.
// Grid 1024 = 128 strips x 8 X-eighths; eighth = bid&7 pins per-XCD L2.
__global__ __launch_bounds__(256, 2) void som_fast(const unsigned short* __restrict__ Xfh,
                                                   const unsigned short* __restrict__ Xfl,
                                                   const unsigned short* __restrict__ Wfh,
                                                   const unsigned short* __restrict__ Wfl,
                                                   const float* __restrict__ w2,
                                                   unsigned long long* __restrict__ packed) {
    __shared__ __align__(16) char lds[65536]; // B_lo strip; read-only after init

    const int t    = threadIdx.x;
    const int lane = t & 63;
    const int wvu  = __builtin_amdgcn_readfirstlane(t >> 6);
    const int wr   = wvu >> 1, wc = wvu & 1;
    const int fr   = lane & 15;
    const int kq   = lane >> 4;

    const int bid = blockIdx.x;  // 0..1023
    const int e   = bid & 7;     // X eighth (1024 rows) -> one per XCD
    const int s   = bid >> 3;    // W strip (128 cols), 0..127

    // ---- one-time setup ----
    // B_hi: cols [s*128 + wc*64, +64) = chunks s*8 + wc*4 + j, all 8 ks
    const char* bhbase = (const char*)Wfh + (size_t)(s * 8 + wc * 4) * 8192 + lane * 16;
    short8 bh[4][8];
    #pragma unroll
    for (int j = 0; j < 4; ++j)
        #pragma unroll
        for (int ks = 0; ks < 8; ++ks)
            bh[j][ks] = *(const short8*)(bhbase + j * 8192 + ks * 1024);

    // B_lo strip: 64KB contiguous in fragment-major Wfl -> LDS (linear copy)
    {
        const char* wsrc = (const char*)Wfl + (size_t)s * 65536 + t * 16;
        #pragma unroll
        for (int k = 0; k < 16; ++k)
            gl16(wsrc + k * 4096, lds + t * 16 + k * 4096);
    }

    float w2v[4];
    #pragma unroll
    for (int j = 0; j < 4; ++j)
        w2v[j] = w2[s * 128 + wc * 64 + j * 16 + fr];

    __syncthreads(); // B_lo resident; no barriers after this point

    const char* blbase = lds + wc * 4 * 8192 + lane * 16;
    const char* ahbase = (const char*)Xfh + (size_t)(e * 64 + wr * 4) * 8192 + lane * 16;
    const char* albase = (const char*)Xfl + (size_t)(e * 64 + wr * 4) * 8192 + lane * 16;

    for (int p = 0; p < 8; ++p) { // 128 X rows per pass
        const size_t poff = (size_t)p * 65536; // 8 chunks * 8192B

        f32x4 acc[4][4];
        #pragma unroll
        for (int i = 0; i < 4; ++i)
            #pragma unroll
            for (int j = 0; j < 4; ++j)
                acc[i][j] = (f32x4){0.f, 0.f, 0.f, 0.f};

        #pragma unroll
        for (int ks = 0; ks < 8; ++ks) {
            short8 ah[4], al[4], bl[4];
            #pragma unroll
            for (int i = 0; i < 4; ++i) {
                ah[i] = *(const short8*)(ahbase + poff + i * 8192 + ks * 1024);
                al[i] = *(const short8*)(albase + poff + i * 8192 + ks * 1024);
            }
            #pragma unroll
            for (int j = 0; j < 4; ++j)
                bl[j] = *(const short8*)(blbase + j * 8192 + ks * 1024);

            __builtin_amdgcn_s_setprio(1);
            #pragma unroll
            for (int i = 0; i < 4; ++i)
                #pragma unroll
                for (int j = 0; j < 4; ++j) {
                    acc[i][j] = __builtin_amdgcn_mfma_f32_16x16x32_bf16(ah[i], bh[j][ks], acc[i][j], 0, 0, 0);
                    acc[i][j] = __builtin_amdgcn_mfma_f32_16x16x32_bf16(ah[i], bl[j],     acc[i][j], 0, 0, 0);
                    acc[i][j] = __builtin_amdgcn_mfma_f32_16x16x32_bf16(al[i], bh[j][ks], acc[i][j], 0, 0, 0);
                }
            __builtin_amdgcn_s_setprio(0);
        }

        // epilogue for this pass: s = w2[n] - 2*dot; min+argmin; atomicMin
        const int rowbase = e * 1024 + p * 128 + wr * 64;
        #pragma unroll
        for (int i = 0; i < 4; ++i) {
            #pragma unroll
            for (int r = 0; r < 4; ++r) {
                const int row = rowbase + i * 16 + kq * 4 + r; // C: row=(l>>4)*4+reg
                float best = 3.4e38f;
                unsigned bidx = 0u;
                #pragma unroll
                for (int j = 0; j < 4; ++j) {
                    const unsigned n = (unsigned)(s * 128 + wc * 64 + j * 16 + fr); // C: col=l&15
                    const float sc = fmaf(-2.0f, acc[i][j][r], w2v[j]);
                    if (sc < best) { best = sc; bidx = n; }
                }
                #pragma unroll
                for (int m = 1; m <= 8; m <<= 1) { // reduce across 16 fr-lanes
                    float    ov = __shfl_xor(best, m);
                    unsigned oi = (unsigned)__shfl_xor((int)bidx, m);
                    if (ov < best || (ov == best && oi < bidx)) { best = ov; bidx = oi; }
                }
                if (fr == 0) atomicMin(&packed[row], packKey(best, bidx));
            }
        }
    }
}

// ---------------- fallback path (round-2 kernel, proven) ----------------

__device__ __forceinline__ unsigned packhi2(float a, float b) {
    return (__float_as_uint(a) >> 16) | (__float_as_uint(b) & 0xFFFF0000u);
}
__device__ __forceinline__ unsigned packlo2(float a, float b) {
    float ah = __uint_as_float(__float_as_uint(a) & 0xFFFF0000u);
    float bh = __uint_as_float(__float_as_uint(b) & 0xFFFF0000u);
    return (__float_as_uint(a - ah) >> 16) | (__float_as_uint(b - bh) & 0xFFFF0000u);
}
__device__ __forceinline__ uint4 mku4(unsigned a, unsigned b, unsigned c, unsigned d) {
    uint4 r; r.x = a; r.y = b; r.z = c; r.w = d; return r;
}
__device__ __forceinline__ uint4 hi8(float4 p, float4 q) {
    return mku4(packhi2(p.x, p.y), packhi2(p.z, p.w), packhi2(q.x, q.y), packhi2(q.z, q.w));
}
__device__ __forceinline__ uint4 lo8(float4 p, float4 q) {
    return mku4(packlo2(p.x, p.y), packlo2(p.z, p.w), packlo2(q.x, q.y), packlo2(q.z, q.w));
}
__device__ __forceinline__ int lb(int row, int slot) {
    return row * 64 + ((slot ^ ((row >> 1) & 3)) << 4);
}

__global__ __launch_bounds__(256, 2) void som_mfma(const float* __restrict__ X,
                                                   const float* __restrict__ W,
                                                   const float* __restrict__ w2,
                                                   unsigned long long* __restrict__ packed) {
    __shared__ char lds[4 * 8192];
    char* Ahp = lds;
    char* Alp = lds + 8192;
    char* Bhp = lds + 16384;
    char* Blp = lds + 24576;

    const int t     = threadIdx.x;
    const int lane  = t & 63;
    const int wv    = t >> 6;
    const int wr    = wv >> 1, wc = wv & 1;
    const int fr    = lane & 15;
    const int kslot = lane >> 4;

    const int rb = blockIdx.x >> 7;
    const int cb = blockIdx.x & 127;
    const int r0 = rb * 128, c0 = cb * 128;

    const int sr = t >> 1;
    const int sh = t & 1;
    const float* xg = (const float*)X + (size_t)(r0 + sr) * V_DIM + sh * 16;
    const float* wg = (const float*)W + (size_t)(c0 + sr) * V_DIM + sh * 16;

    float4 pa[4], pb[4];
    #pragma unroll
    for (int q = 0; q < 4; ++q) { pa[q] = ((const float4*)xg)[q]; pb[q] = ((const float4*)wg)[q]; }

    f32x4 acc[4][4];
    #pragma unroll
    for (int i = 0; i < 4; ++i)
        #pragma unroll
        for (int j = 0; j < 4; ++j) acc[i][j] = (f32x4){0.f, 0.f, 0.f, 0.f};

    for (int ks = 0; ks < 8; ++ks) {
        uint4 cah0 = hi8(pa[0], pa[1]), cah1 = hi8(pa[2], pa[3]);
        uint4 cal0 = lo8(pa[0], pa[1]), cal1 = lo8(pa[2], pa[3]);
        uint4 cbh0 = hi8(pb[0], pb[1]), cbh1 = hi8(pb[2], pb[3]);
        uint4 cbl0 = lo8(pb[0], pb[1]), cbl1 = lo8(pb[2], pb[3]);

        __syncthreads();
        *(uint4*)(Ahp + lb(sr, 2 * sh))     = cah0;
        *(uint4*)(Ahp + lb(sr, 2 * sh + 1)) = cah1;
        *(uint4*)(Alp + lb(sr, 2 * sh))     = cal0;
        *(uint4*)(Alp + lb(sr, 2 * sh + 1)) = cal1;
        *(uint4*)(Bhp + lb(sr, 2 * sh))     = cbh0;
        *(uint4*)(Bhp + lb(sr, 2 * sh + 1)) = cbh1;
        *(uint4*)(Blp + lb(sr, 2 * sh))     = cbl0;
        *(uint4*)(Blp + lb(sr, 2 * sh + 1)) = cbl1;
        __syncthreads();

        if (ks + 1 < 8) {
            const float* xn = xg + (ks + 1) * 32;
            const float* wn = wg + (ks + 1) * 32;
            #pragma unroll
            for (int q = 0; q < 4; ++q) { pa[q] = ((const float4*)xn)[q]; pb[q] = ((const float4*)wn)[q]; }
        }

        short8 fah[4], fal[4], fbh[4], fbl[4];
        #pragma unroll
        for (int i = 0; i < 4; ++i) {
            int row = wr * 64 + i * 16 + fr;
            fah[i] = *(const short8*)(Ahp + lb(row, kslot));
            fal[i] = *(const short8*)(Alp + lb(row, kslot));
        }
        #pragma unroll
        for (int j = 0; j < 4; ++j) {
            int col = wc * 64 + j * 16 + fr;
            fbh[j] = *(const short8*)(Bhp + lb(col, kslot));
            fbl[j] = *(const short8*)(Blp + lb(col, kslot));
        }
        #pragma unroll
        for (int i = 0; i < 4; ++i)
            #pragma unroll
            for (int j = 0; j < 4; ++j) {
                acc[i][j] = __builtin_amdgcn_mfma_f32_16x16x32_bf16(fah[i], fbh[j], acc[i][j], 0, 0, 0);
                acc[i][j] = __builtin_amdgcn_mfma_f32_16x16x32_bf16(fah[i], fbl[j], acc[i][j], 0, 0, 0);
                acc[i][j] = __builtin_amdgcn_mfma_f32_16x16x32_bf16(fal[i], fbh[j], acc[i][j], 0, 0, 0);
            }
    }

    float w2v[4];
    #pragma unroll
    for (int j = 0; j < 4; ++j) w2v[j] = w2[c0 + wc * 64 + j * 16 + fr];

    #pragma unroll
    for (int i = 0; i < 4; ++i) {
        #pragma unroll
        for (int r = 0; r < 4; ++r) {
            const int row = r0 + wr * 64 + i * 16 + kslot * 4 + r;
            float best = 3.4e38f;
            unsigned bidx = 0u;
            #pragma unroll
            for (int j = 0; j < 4; ++j) {
                const unsigned n = (unsigned)(c0 + wc * 64 + j * 16 + fr);
                const float s = fmaf(-2.0f, acc[i][j][r], w2v[j]);
                if (s < best) { best = s; bidx = n; }
            }
            #pragma unroll
            for (int m = 1; m <= 8; m <<= 1) {
                float    ov = __shfl_xor(best, m);
                unsigned oi = (unsigned)__shfl_xor((int)bidx, m);
                if (ov < best || (ov == best && oi < bidx)) { best = ov; bidx = oi; }
            }
            if (fr == 0) atomicMin(&packed[row], packKey(best, bidx));
        }
    }
}

__global__ __launch_bounds__(256) void finalize(const float* __restrict__ X,
                                                const float* __restrict__ loc,
                                                const unsigned long long* __restrict__ packed,
                                                float* __restrict__ out) {
    int lane = threadIdx.x & 63;
    int wv   = threadIdx.x >> 6;
    int b    = blockIdx.x * 4 + wv;
    float4 v = ((const float4*)(X + (size_t)b * V_DIM))[lane];
    float x2 = v.x * v.x + v.y * v.y + v.z * v.z + v.w * v.w;
    #pragma unroll
    for (int m = 32; m >= 1; m >>= 1) x2 += __shfl_xor(x2, m);
    if (lane == 0) {
        unsigned long long p = packed[b];
        unsigned key = (unsigned)(p >> 32);
        unsigned idx = (unsigned)(p & 0xFFFFFFFFu);
        unsigned sb  = (key & 0x80000000u) ? (key & 0x7FFFFFFFu) : ~key;
        float s  = __uint_as_float(sb);
        float d2 = fmaxf(x2 + s, 0.0f);
        out[2 * b]     = loc[2 * idx];
        out[2 * b + 1] = loc[2 * idx + 1];
        out[2 * B_DIM + b] = sqrtf(d2);
    }
}

extern "C" void kernel_launch(void* const* d_in, const int* in_sizes, int n_in,
                              void* d_out, int out_size, void* d_ws, size_t ws_size,
                              hipStream_t stream) {
    const float* X = (const float*)d_in[0];   // [8192,256]
    const float* W = (const float*)d_in[1];   // [16384,256]
    const float* L = (const float*)d_in[2];   // [16384,2]
    float* out = (float*)d_out;

    float* w2 = (float*)((char*)d_ws + WS_W2_OFF);
    unsigned long long* packed = (unsigned long long*)((char*)d_ws + WS_PACKED_OFF);

    hipMemsetAsync(packed, 0xFF, B_DIM * sizeof(unsigned long long), stream);
    w2_kernel<<<N_DIM / 4, 256, 0, stream>>>(W, w2);

    if (ws_size >= (size_t)WS_FAST_NEED) {
        unsigned short* Xfh = (unsigned short*)((char*)d_ws + WS_PLANES_OFF);
        unsigned short* Xfl = (unsigned short*)((char*)Xfh + XPLANE_BYTES);
        unsigned short* Wfh = (unsigned short*)((char*)Xfl + XPLANE_BYTES);
        unsigned short* Wfl = (unsigned short*)((char*)Wfh + WPLANE_BYTES);
        convert_planes<<<3072, 256, 0, stream>>>(X, W, Xfh, Xfl, Wfh, Wfl);
        som_fast<<<1024, 256, 0, stream>>>(Xfh, Xfl, Wfh, Wfl, w2, packed);
    } else {
        som_mfma<<<(B_DIM / 128) * (N_DIM / 128), 256, 0, stream>>>(X, W, w2, packed);
    }
    finalize<<<B_DIM / 4, 256, 0, stream>>>(X, L, packed, out);
}

// Round 12
// 255.153 us; speedup vs baseline: 1.7341x; 1.7341x over previous
//
#include <hip/hip_runtime.h>
#include <stdint.h>

// SOM BMU search: B=8192 inputs [B,256], codebook [16384,256].
// argmin_n ||x-w_n|| == argmin_n (w2[n] - 2 x.w_n)  (x2 per-row constant).
// Engine: bf16 hi/lo split GEMM on MFMA (xh.wh + xh.wl + xl.wh).
// R12: faithful m201-style 256x256 / 8-wave / phase-interleaved kernel.
// Fragment-major ws (R10 layout) doubles as the LDS image: gl16 staging is
// linear, ds_read_b128 fragments are conflict-free, no swizzle needed.
// 6 phases x 16 MFMA per K-tile; counted staging flies 2-5 phases before
// its drain; per-phase s_barrier + lgkmcnt(0) + setprio MFMA cluster.

#define B_DIM 8192
#define V_DIM 256
#define N_DIM 16384

#define WS_W2_OFF     0
#define WS_PACKED_OFF 65536
#define WS_PLANES_OFF 131072
#define XPLANE_BYTES  (B_DIM * V_DIM * 2)   // 4MB
#define WPLANE_BYTES  (N_DIM * V_DIM * 2)   // 8MB
#define WS_FAST_NEED  (WS_PLANES_OFF + 2 * XPLANE_BYTES + 2 * WPLANE_BYTES)

typedef __attribute__((ext_vector_type(8))) short short8;
typedef __attribute__((ext_vector_type(4))) float f32x4;

__device__ __forceinline__ unsigned long long packKey(float s, unsigned idx) {
    unsigned u = __float_as_uint(s);
    u = (u & 0x80000000u) ? ~u : (u | 0x80000000u);
    return ((unsigned long long)u << 32) | (unsigned long long)idx;
}

__global__ __launch_bounds__(256) void w2_kernel(const float* __restrict__ W,
                                                 float* __restrict__ w2) {
    int lane = threadIdx.x & 63;
    int wv   = threadIdx.x >> 6;
    int n    = blockIdx.x * 4 + wv;
    float4 v = ((const float4*)(W + (size_t)n * V_DIM))[lane];
    float s = v.x * v.x + v.y * v.y + v.z * v.z + v.w * v.w;
    #pragma unroll
    for (int m = 32; m >= 1; m >>= 1) s += __shfl_xor(s, m);
    if (lane == 0) w2[n] = s;
}

// ---------------- fast path ----------------

__device__ __forceinline__ unsigned bfrn(float x) { // RNE f32->bf16
    unsigned u = __float_as_uint(x);
    return (u + 0x7FFFu + ((u >> 16) & 1u)) >> 16;
}
__device__ __forceinline__ float bf2f(unsigned h) { return __uint_as_float(h << 16); }

__device__ __forceinline__ void hilo8(const float4& a, const float4& b,
                                      uint4& hp, uint4& lp) {
    float v[8] = {a.x, a.y, a.z, a.w, b.x, b.y, b.z, b.w};
    unsigned hi[8], lo[8];
    #pragma unroll
    for (int i = 0; i < 8; ++i) {
        hi[i] = bfrn(v[i]);
        lo[i] = bfrn(v[i] - bf2f(hi[i]));
    }
    hp.x = hi[0] | (hi[1] << 16); hp.y = hi[2] | (hi[3] << 16);
    hp.z = hi[4] | (hi[5] << 16); hp.w = hi[6] | (hi[7] << 16);
    lp.x = lo[0] | (lo[1] << 16); lp.y = lo[2] | (lo[3] << 16);
    lp.z = lo[4] | (lo[5] << 16); lp.w = lo[6] | (lo[7] << 16);
}

// Fragment-major planes (R10 layout, proven):
//   F[chunk16][ks][lane][8bf16], addr = ((chunk*8 + ks)*64 + lane)*16B
//   chunk = row/16; lane l covers row chunk*16+(l&15), k = ks*32+(l>>4)*8..+8
__global__ __launch_bounds__(256) void convert_planes(const float* __restrict__ X,
                                                      const float* __restrict__ W,
                                                      unsigned short* __restrict__ Xfh,
                                                      unsigned short* __restrict__ Xfl,
                                                      unsigned short* __restrict__ Wfh,
                                                      unsigned short* __restrict__ Wfl) {
    const int gid = blockIdx.x * 256 + threadIdx.x;
    const float* src;
    unsigned short *dh, *dl;
    int tid;
    if (blockIdx.x < 1024) { // X: 512 chunks * 8 ks * 64 lanes = 262144
        tid = gid;
        const int lane = tid & 63, ck = tid >> 6;
        const int ks = ck & 7, chunk = ck >> 3;
        const int row = chunk * 16 + (lane & 15);
        const int k0  = ks * 32 + (lane >> 4) * 8;
        src = X + (size_t)row * V_DIM + k0;
        dh = Xfh; dl = Xfl;
    } else {                 // W: 1024 chunks -> 524288
        tid = gid - 262144;
        const int lane = tid & 63, ck = tid >> 6;
        const int ks = ck & 7, chunk = ck >> 3;
        const int row = chunk * 16 + (lane & 15);
        const int k0  = ks * 32 + (lane >> 4) * 8;
        src = W + (size_t)row * V_DIM + k0;
        dh = Wfh; dl = Wfl;
    }
    float4 a = ((const float4*)src)[0];
    float4 b = ((const float4*)src)[1];
    uint4 hp, lp; hilo8(a, b, hp, lp);
    *(uint4*)(dh + (size_t)tid * 8) = hp;
    *(uint4*)(dl + (size_t)tid * 8) = lp;
}

__device__ __forceinline__ void gl16(const void* g, void* l) {
    __builtin_amdgcn_global_load_lds((const __attribute__((address_space(1))) unsigned int*)g,
                                     (__attribute__((address_space(3))) unsigned int*)l,
                                     16, 0, 0);
}

#define BARX()   asm volatile("s_barrier" ::: "memory")
#define LGKM0()  asm volatile("s_waitcnt lgkmcnt(0)" ::: "memory")
#define VMC0()   asm volatile("s_waitcnt vmcnt(0)" ::: "memory")
#define SCHED0() __builtin_amdgcn_sched_barrier(0)

// 512 threads = 8 waves (2 row-halves x 4 col-quarters), tile 256x256.
// LDS: 2 x 64KB buffers, each [Ah|Al|Bh|Bl] x 16 chunks x 1KB (fragment-major).
__global__ __launch_bounds__(512, 1) void som_fast(const unsigned short* __restrict__ Xfh,
                                                   const unsigned short* __restrict__ Xfl,
                                                   const unsigned short* __restrict__ Wfh,
                                                   const unsigned short* __restrict__ Wfl,
                                                   const float* __restrict__ w2,
                                                   unsigned long long* __restrict__ packed) {
    __shared__ __align__(16) char lds[131072];

    const int t    = threadIdx.x;
    const int lane = t & 63;
    const int wvu  = __builtin_amdgcn_readfirstlane(t >> 6); // 0..7, SGPR
    const int wr   = wvu >> 2;   // row half (128 rows)
    const int wc   = wvu & 3;    // col quarter (64 cols)
    const int fr   = lane & 15;
    const int kq   = lane >> 4;
    const int lo   = lane * 16;

    // bijective XCD swizzle: XCD x runs rb in [4x,4x+4); 32-CU window = 4rb x 8cb
    // -> 1MB A + 2MB B < 4MB per-XCD L2.
    const int bid = blockIdx.x;           // 0..2047
    const int xcd = bid & 7, q = bid >> 3; // q 0..255
    const int rb  = xcd * 4 + (q & 3);    // 0..31
    const int cb  = q >> 2;               // 0..63

    char* buf0 = lds;
    char* buf1 = lds + 65536;

    // staging: wave w owns chunk list indices [w*8, w*8+8) of
    // [Ah0..15 | Al0..15 | Bh0..15 | Bl0..15]; one gl16 stages one 1KB chunk.
#define STAGE2(cc, ksv, DST)                                                      \
    do {                                                                          \
        _Pragma("unroll")                                                         \
        for (int c = (cc); c < (cc) + 2; ++c) {                                   \
            const int gidx = wvu * 8 + c;                                         \
            const int pl   = gidx >> 4;                                           \
            const int idx  = gidx & 15;                                           \
            const char* sb = (pl == 0) ? (const char*)Xfh                         \
                           : (pl == 1) ? (const char*)Xfl                         \
                           : (pl == 2) ? (const char*)Wfh : (const char*)Wfl;     \
            const int cg   = ((pl < 2) ? rb : cb) * 16 + idx;                     \
            gl16(sb + (((size_t)(cg * 8 + (ksv))) << 10) + lo,                    \
                 (DST) + pl * 16384 + idx * 1024 + lo);                           \
        }                                                                         \
    } while (0)

    f32x4 acc[8][4];
    #pragma unroll
    for (int i = 0; i < 8; ++i)
        #pragma unroll
        for (int j = 0; j < 4; ++j)
            acc[i][j] = (f32x4){0.f, 0.f, 0.f, 0.f};

    short8 fa[8], bh[4], bl[4];

#define RD_AH(CUR, i) fa[i] = *(const short8*)((CUR) + (wr * 8 + (i)) * 1024 + lo)
#define RD_AL(CUR, i) fa[i] = *(const short8*)((CUR) + 16384 + (wr * 8 + (i)) * 1024 + lo)
#define RD_BH(CUR, j) bh[j] = *(const short8*)((CUR) + 32768 + (wc * 4 + (j)) * 1024 + lo)
#define RD_BL(CUR, j) bl[j] = *(const short8*)((CUR) + 49152 + (wc * 4 + (j)) * 1024 + lo)

#define MFMA16(FB, j0)                                                            \
    do {                                                                          \
        _Pragma("unroll")                                                         \
        for (int i = 0; i < 8; ++i)                                               \
            _Pragma("unroll")                                                     \
            for (int jj = 0; jj < 2; ++jj)                                        \
                acc[i][(j0) + jj] = __builtin_amdgcn_mfma_f32_16x16x32_bf16(      \
                    fa[i], FB[(j0) + jj], acc[i][(j0) + jj], 0, 0, 0);            \
    } while (0)

#define PHASE(BODY_READS, BODY_STAGE, FB, j0)                                     \
    do {                                                                          \
        BODY_READS;                                                               \
        BODY_STAGE;                                                               \
        BARX(); LGKM0(); SCHED0();                                                \
        __builtin_amdgcn_s_setprio(1);                                            \
        MFMA16(FB, j0);                                                           \
        __builtin_amdgcn_s_setprio(0);                                            \
    } while (0)

    // KSTEP: 6 phases. Per-acc term order hh -> hl -> lh (bitwise == R10).
#define KSTEP(CUR, NXT, ksv)                                                      \
    do {                                                                          \
        const int more = (ksv) < 7;                                               \
        /* P0: hh j01 */                                                          \
        PHASE({ _Pragma("unroll") for (int i = 0; i < 8; ++i) RD_AH(CUR, i);      \
                RD_BH(CUR, 0); RD_BH(CUR, 1); },                                  \
              { if (more) STAGE2(0, (ksv) + 1, NXT); }, bh, 0);                   \
        /* P1: hh j23 */                                                          \
        PHASE({ RD_BH(CUR, 2); RD_BH(CUR, 3); },                                  \
              { if (more) STAGE2(2, (ksv) + 1, NXT); }, bh, 2);                   \
        /* P2: hl j01 */                                                          \
        PHASE({ RD_BL(CUR, 0); RD_BL(CUR, 1); },                                  \
              { if (more) STAGE2(4, (ksv) + 1, NXT); }, bl, 0);                   \
        /* P3: hl j23 */                                                          \
        PHASE({ RD_BL(CUR, 2); RD_BL(CUR, 3); },                                  \
              { if (more) STAGE2(6, (ksv) + 1, NXT); }, bl, 2);                   \
        /* P4: lh j01 (fa reloaded with Al) */                                    \
        PHASE({ _Pragma("unroll") for (int i = 0; i < 8; ++i) RD_AL(CUR, i); },   \
              {}, bh, 0);                                                         \
        /* P5: lh j23 */                                                          \
        PHASE({}, {}, bh, 2);                                                     \
        VMC0();  /* ks+1 staging landed (issued 2-5 phases ago: free) */          \
        BARX();  /* all waves done reading CUR; NXT valid for all */              \
    } while (0)

    // prologue: stage tile 0 into buf0
    STAGE2(0, 0, buf0); STAGE2(2, 0, buf0); STAGE2(4, 0, buf0); STAGE2(6, 0, buf0);
    VMC0();
    BARX();

    for (int kk = 0; kk < 4; ++kk) {
        KSTEP(buf0, buf1, 2 * kk);
        KSTEP(buf1, buf0, 2 * kk + 1);
    }
#undef KSTEP
#undef PHASE
#undef MFMA16
#undef RD_AH
#undef RD_AL
#undef RD_BH
#undef RD_BL
#undef STAGE2

    // epilogue: s = w2[n] - 2*dot; per-row min+argmin; merge via atomicMin
    float w2v[4];
    #pragma unroll
    for (int j = 0; j < 4; ++j)
        w2v[j] = w2[cb * 256 + wc * 64 + j * 16 + fr];

    #pragma unroll
    for (int i = 0; i < 8; ++i) {
        #pragma unroll
        for (int r = 0; r < 4; ++r) {
            const int row = rb * 256 + wr * 128 + i * 16 + kq * 4 + r; // C: row=(l>>4)*4+reg
            float best = 3.4e38f;
            unsigned bidx = 0u;
            #pragma unroll
            for (int j = 0; j < 4; ++j) {
                const unsigned n = (unsigned)(cb * 256 + wc * 64 + j * 16 + fr); // C: col=l&15
                const float sc = fmaf(-2.0f, acc[i][j][r], w2v[j]);
                if (sc < best) { best = sc; bidx = n; }
            }
            #pragma unroll
            for (int m = 1; m <= 8; m <<= 1) { // reduce across 16 fr-lanes
                float    ov = __shfl_xor(best, m);
                unsigned oi = (unsigned)__shfl_xor((int)bidx, m);
                if (ov < best || (ov == best && oi < bidx)) { best = ov; bidx = oi; }
            }
            if (fr == 0) atomicMin(&packed[row], packKey(best, bidx));
        }
    }
}

// ---------------- fallback path (round-2 kernel, proven) ----------------

__device__ __forceinline__ unsigned packhi2(float a, float b) {
    return (__float_as_uint(a) >> 16) | (__float_as_uint(b) & 0xFFFF0000u);
}
__device__ __forceinline__ unsigned packlo2(float a, float b) {
    float ah = __uint_as_float(__float_as_uint(a) & 0xFFFF0000u);
    float bh = __uint_as_float(__float_as_uint(b) & 0xFFFF0000u);
    return (__float_as_uint(a - ah) >> 16) | (__float_as_uint(b - bh) & 0xFFFF0000u);
}
__device__ __forceinline__ uint4 mku4(unsigned a, unsigned b, unsigned c, unsigned d) {
    uint4 r; r.x = a; r.y = b; r.z = c; r.w = d; return r;
}
__device__ __forceinline__ uint4 hi8(float4 p, float4 q) {
    return mku4(packhi2(p.x, p.y), packhi2(p.z, p.w), packhi2(q.x, q.y), packhi2(q.z, q.w));
}
__device__ __forceinline__ uint4 lo8(float4 p, float4 q) {
    return mku4(packlo2(p.x, p.y), packlo2(p.z, p.w), packlo2(q.x, q.y), packlo2(q.z, q.w));
}
__device__ __forceinline__ int lb(int row, int slot) {
    return row * 64 + ((slot ^ ((row >> 1) & 3)) << 4);
}

__global__ __launch_bounds__(256, 2) void som_mfma(const float* __restrict__ X,
                                                   const float* __restrict__ W,
                                                   const float* __restrict__ w2,
                                                   unsigned long long* __restrict__ packed) {
    __shared__ char lds[4 * 8192];
    char* Ahp = lds;
    char* Alp = lds + 8192;
    char* Bhp = lds + 16384;
    char* Blp = lds + 24576;

    const int t     = threadIdx.x;
    const int lane  = t & 63;
    const int wv    = t >> 6;
    const int wr    = wv >> 1, wc = wv & 1;
    const int fr    = lane & 15;
    const int kslot = lane >> 4;

    const int rb = blockIdx.x >> 7;
    const int cb = blockIdx.x & 127;
    const int r0 = rb * 128, c0 = cb * 128;

    const int sr = t >> 1;
    const int sh = t & 1;
    const float* xg = (const float*)X + (size_t)(r0 + sr) * V_DIM + sh * 16;
    const float* wg = (const float*)W + (size_t)(c0 + sr) * V_DIM + sh * 16;

    float4 pa[4], pb[4];
    #pragma unroll
    for (int q = 0; q < 4; ++q) { pa[q] = ((const float4*)xg)[q]; pb[q] = ((const float4*)wg)[q]; }

    f32x4 acc[4][4];
    #pragma unroll
    for (int i = 0; i < 4; ++i)
        #pragma unroll
        for (int j = 0; j < 4; ++j) acc[i][j] = (f32x4){0.f, 0.f, 0.f, 0.f};

    for (int ks = 0; ks < 8; ++ks) {
        uint4 cah0 = hi8(pa[0], pa[1]), cah1 = hi8(pa[2], pa[3]);
        uint4 cal0 = lo8(pa[0], pa[1]), cal1 = lo8(pa[2], pa[3]);
        uint4 cbh0 = hi8(pb[0], pb[1]), cbh1 = hi8(pb[2], pb[3]);
        uint4 cbl0 = lo8(pb[0], pb[1]), cbl1 = lo8(pb[2], pb[3]);

        __syncthreads();
        *(uint4*)(Ahp + lb(sr, 2 * sh))     = cah0;
        *(uint4*)(Ahp + lb(sr, 2 * sh + 1)) = cah1;
        *(uint4*)(Alp + lb(sr, 2 * sh))     = cal0;
        *(uint4*)(Alp + lb(sr, 2 * sh + 1)) = cal1;
        *(uint4*)(Bhp + lb(sr, 2 * sh))     = cbh0;
        *(uint4*)(Bhp + lb(sr, 2 * sh + 1)) = cbh1;
        *(uint4*)(Blp + lb(sr, 2 * sh))     = cbl0;
        *(uint4*)(Blp + lb(sr, 2 * sh + 1)) = cbl1;
        __syncthreads();

        if (ks + 1 < 8) {
            const float* xn = xg + (ks + 1) * 32;
            const float* wn = wg + (ks + 1) * 32;
            #pragma unroll
            for (int q = 0; q < 4; ++q) { pa[q] = ((const float4*)xn)[q]; pb[q] = ((const float4*)wn)[q]; }
        }

        short8 fah[4], fal[4], fbh[4], fbl[4];
        #pragma unroll
        for (int i = 0; i < 4; ++i) {
            int row = wr * 64 + i * 16 + fr;
            fah[i] = *(const short8*)(Ahp + lb(row, kslot));
            fal[i] = *(const short8*)(Alp + lb(row, kslot));
        }
        #pragma unroll
        for (int j = 0; j < 4; ++j) {
            int col = wc * 64 + j * 16 + fr;
            fbh[j] = *(const short8*)(Bhp + lb(col, kslot));
            fbl[j] = *(const short8*)(Blp + lb(col, kslot));
        }
        #pragma unroll
        for (int i = 0; i < 4; ++i)
            #pragma unroll
            for (int j = 0; j < 4; ++j) {
                acc[i][j] = __builtin_amdgcn_mfma_f32_16x16x32_bf16(fah[i], fbh[j], acc[i][j], 0, 0, 0);
                acc[i][j] = __builtin_amdgcn_mfma_f32_16x16x32_bf16(fah[i], fbl[j], acc[i][j], 0, 0, 0);
                acc[i][j] = __builtin_amdgcn_mfma_f32_16x16x32_bf16(fal[i], fbh[j], acc[i][j], 0, 0, 0);
            }
    }

    float w2v[4];
    #pragma unroll
    for (int j = 0; j < 4; ++j) w2v[j] = w2[c0 + wc * 64 + j * 16 + fr];

    #pragma unroll
    for (int i = 0; i < 4; ++i) {
        #pragma unroll
        for (int r = 0; r < 4; ++r) {
            const int row = r0 + wr * 64 + i * 16 + kslot * 4 + r;
            float best = 3.4e38f;
            unsigned bidx = 0u;
            #pragma unroll
            for (int j = 0; j < 4; ++j) {
                const unsigned n = (unsigned)(c0 + wc * 64 + j * 16 + fr);
                const float s = fmaf(-2.0f, acc[i][j][r], w2v[j]);
                if (s < best) { best = s; bidx = n; }
            }
            #pragma unroll
            for (int m = 1; m <= 8; m <<= 1) {
                float    ov = __shfl_xor(best, m);
                unsigned oi = (unsigned)__shfl_xor((int)bidx, m);
                if (ov < best || (ov == best && oi < bidx)) { best = ov; bidx = oi; }
            }
            if (fr == 0) atomicMin(&packed[row], packKey(best, bidx));
        }
    }
}

__global__ __launch_bounds__(256) void finalize(const float* __restrict__ X,
                                                const float* __restrict__ loc,
                                                const unsigned long long* __restrict__ packed,
                                                float* __restrict__ out) {
    int lane = threadIdx.x & 63;
    int wv   = threadIdx.x >> 6;
    int b    = blockIdx.x * 4 + wv;
    float4 v = ((const float4*)(X + (size_t)b * V_DIM))[lane];
    float x2 = v.x * v.x + v.y * v.y + v.z * v.z + v.w * v.w;
    #pragma unroll
    for (int m = 32; m >= 1; m >>= 1) x2 += __shfl_xor(x2, m);
    if (lane == 0) {
        unsigned long long p = packed[b];
        unsigned key = (unsigned)(p >> 32);
        unsigned idx = (unsigned)(p & 0xFFFFFFFFu);
        unsigned sb  = (key & 0x80000000u) ? (key & 0x7FFFFFFFu) : ~key;
        float s  = __uint_as_float(sb);
        float d2 = fmaxf(x2 + s, 0.0f);
        out[2 * b]     = loc[2 * idx];
        out[2 * b + 1] = loc[2 * idx + 1];
        out[2 * B_DIM + b] = sqrtf(d2);
    }
}

extern "C" void kernel_launch(void* const* d_in, const int* in_sizes, int n_in,
                              void* d_out, int out_size, void* d_ws, size_t ws_size,
                              hipStream_t stream) {
    const float* X = (const float*)d_in[0];   // [8192,256]
    const float* W = (const float*)d_in[1];   // [16384,256]
    const float* L = (const float*)d_in[2];   // [16384,2]
    float* out = (float*)d_out;

    float* w2 = (float*)((char*)d_ws + WS_W2_OFF);
    unsigned long long* packed = (unsigned long long*)((char*)d_ws + WS_PACKED_OFF);

    hipMemsetAsync(packed, 0xFF, B_DIM * sizeof(unsigned long long), stream);
    w2_kernel<<<N_DIM / 4, 256, 0, stream>>>(W, w2);

    if (ws_size >= (size_t)WS_FAST_NEED) {
        unsigned short* Xfh = (unsigned short*)((char*)d_ws + WS_PLANES_OFF);
        unsigned short* Xfl = (unsigned short*)((char*)Xfh + XPLANE_BYTES);
        unsigned short* Wfh = (unsigned short*)((char*)Xfl + XPLANE_BYTES);
        unsigned short* Wfl = (unsigned short*)((char*)Wfh + WPLANE_BYTES);
        convert_planes<<<3072, 256, 0, stream>>>(X, W, Xfh, Xfl, Wfh, Wfl);
        som_fast<<<(B_DIM / 256) * (N_DIM / 256), 512, 0, stream>>>(Xfh, Xfl, Wfh, Wfl, w2, packed);
    } else {
        som_mfma<<<(B_DIM / 128) * (N_DIM / 128), 256, 0, stream>>>(X, W, w2, packed);
    }
    finalize<<<B_DIM / 4, 256, 0, stream>>>(X, L, packed, out);
}